// Round 4
// baseline (314.278 us; speedup 1.0000x reference)
//
#include <hip/hip_runtime.h>
#include <hip/hip_bf16.h>

#define BB 2
#define NN 2048
#define DD 128
#define HH 8
#define OUTD 256
#define SCALE 0.022097086912079612f  // 1/sqrt(2048)

typedef __bf16 bf16x8 __attribute__((ext_vector_type(8)));
typedef float f32x4 __attribute__((ext_vector_type(4)));
typedef _Float16 f16x8 __attribute__((ext_vector_type(8)));

__device__ __forceinline__ unsigned short f2bf(float f) {
    union { float f; unsigned int u; } v; v.f = f;
    unsigned int r = (v.u + 0x7FFFu + ((v.u >> 16) & 1u)) >> 16;
    return (unsigned short)r;
}
__device__ __forceinline__ float bf2f(unsigned short s) {
    union { unsigned int u; float f; } v; v.u = ((unsigned int)s) << 16;
    return v.f;
}
// async global->LDS, 16 B per lane; lds dst = wave-uniform base + lane*16
__device__ __forceinline__ void gl_lds16(const unsigned short* g, unsigned short* l) {
    __builtin_amdgcn_global_load_lds(
        (const __attribute__((address_space(1))) unsigned int*)g,
        (__attribute__((address_space(3))) unsigned int*)l,
        16, 0, 0);
}

// ---------------- prep: bf16 casts + weight transposes ----------------
__global__ void prep_kernel(const float* __restrict__ X,
                            const float* __restrict__ Wq,
                            const float* __restrict__ Wk,
                            const float* __restrict__ Wv,
                            const float* __restrict__ Wout,
                            unsigned short* __restrict__ Xb,     // [B][N][D]
                            unsigned short* __restrict__ WT,     // [3][H][e][d]
                            unsigned short* __restrict__ WoutT)  // [OUT][H*D]
{
    const int NX  = BB * NN * DD;        // 524288
    const int NW  = 3 * HH * DD * DD;    // 393216
    const int NWO = (HH * DD) * OUTD;    // 262144
    int idx = blockIdx.x * blockDim.x + threadIdx.x;
    if (idx < NX) {
        Xb[idx] = f2bf(X[idx]);
    } else if (idx < NX + NW) {
        int i = idx - NX;
        int mat = i / (HH * DD * DD);
        int r   = i % (HH * DD * DD);
        int h = r / (DD * DD);
        int j = r % (DD * DD);
        int e = j / DD;
        int d = j % DD;
        const float* Wm = (mat == 0) ? Wq : ((mat == 1) ? Wk : Wv);
        WT[i] = f2bf(Wm[h * DD * DD + d * DD + e]);
    } else if (idx < NX + NW + NWO) {
        int i = idx - NX - NW;
        int o = i / (HH * DD);
        int k = i % (HH * DD);
        WoutT[i] = f2bf(Wout[k * OUTD + o]);
    }
}

// ---------------- adjsum: nodeadj.sum(-1) -> bf16 ----------------
__global__ void adjsum_kernel(const float4* __restrict__ adj, unsigned short* __restrict__ s) {
    int idx = blockIdx.x * blockDim.x + threadIdx.x;  // B*N*N threads
    float4 a = adj[idx];
    s[idx] = f2bf((a.x + a.y) + (a.z + a.w));
}

// ---------------- projections q/k/v ----------------
// grid (N/64, B*H, 3); block 256. mat: 0=Q, 1=K, 2=V(transposed output via LDS)
__global__ __launch_bounds__(256) void proj_kernel(
    const unsigned short* __restrict__ Xb,
    const unsigned short* __restrict__ WT,
    const float* __restrict__ bq, const float* __restrict__ bk, const float* __restrict__ bv,
    unsigned short* __restrict__ Qo, unsigned short* __restrict__ Ko,
    unsigned short* __restrict__ Vt)
{
    const int mat = blockIdx.z;
    const int bh  = blockIdx.y;
    const int b = bh >> 3, h = bh & 7;
    const int n0 = blockIdx.x * 64;
    const int tid = threadIdx.x;
    const int lane = tid & 63, wv = tid >> 6;
    const int m = lane & 15, quad = lane >> 4;

    __shared__ unsigned short Wlds[128 * 136];  // [e][d], pad 136; reused for V transpose

    const unsigned short* Wg = WT + ((size_t)mat * HH + h) * (DD * DD);
    #pragma unroll
    for (int i = tid; i < 128 * 16; i += 256) {
        int r = i >> 4, c = i & 15;
        *(uint4*)&Wlds[r * 136 + c * 8] = *(const uint4*)(Wg + r * 128 + c * 8);
    }

    const int row = n0 + wv * 16 + m;
    const unsigned short* Xr = Xb + ((size_t)b * NN + row) * DD;
    bf16x8 af[4];
    #pragma unroll
    for (int kc = 0; kc < 4; ++kc)
        af[kc] = *(const bf16x8*)(Xr + kc * 32 + quad * 8);

    __syncthreads();

    f32x4 acc[8];
    #pragma unroll
    for (int et = 0; et < 8; ++et) acc[et] = (f32x4){0.f, 0.f, 0.f, 0.f};

    #pragma unroll
    for (int kc = 0; kc < 4; ++kc) {
        #pragma unroll
        for (int et = 0; et < 8; ++et) {
            bf16x8 bfrg = *(const bf16x8*)&Wlds[(et * 16 + m) * 136 + kc * 32 + quad * 8];
            acc[et] = __builtin_amdgcn_mfma_f32_16x16x32_bf16(af[kc], bfrg, acc[et], 0, 0, 0);
        }
    }

    const float* bias = (mat == 0) ? bq : ((mat == 1) ? bk : bv);
    if (mat != 2) {
        #pragma unroll
        for (int et = 0; et < 8; ++et) {
            int e = et * 16 + m;
            float bb = bias[h * DD + e];
            #pragma unroll
            for (int reg = 0; reg < 4; ++reg) {
                int r = n0 + wv * 16 + quad * 4 + reg;
                unsigned short v16 = f2bf(acc[et][reg] + bb);
                if (mat == 0) Qo[((size_t)bh * NN + r) * DD + e] = v16;
                else          Ko[((size_t)bh * NN + r) * DD + e] = v16;
            }
        }
    } else {
        // V: transpose through LDS -> coalesced uint4 stores to Vt[bh][e][n]
        __syncthreads();  // everyone done with Wlds MFMA reads
        #pragma unroll
        for (int et = 0; et < 8; ++et) {
            int e = et * 16 + m;
            float bb = bias[h * DD + e];
            #pragma unroll
            for (int reg = 0; reg < 4; ++reg)
                Wlds[(wv * 16 + quad * 4 + reg) * 136 + e] = f2bf(acc[et][reg] + bb);
        }
        __syncthreads();
        const int e = tid >> 1, nh = tid & 1;
        #pragma unroll
        for (int j = 0; j < 4; ++j) {
            unsigned short tmp[8];
            #pragma unroll
            for (int kk = 0; kk < 8; ++kk)
                tmp[kk] = Wlds[(nh * 32 + j * 8 + kk) * 136 + e];
            *(uint4*)(Vt + ((size_t)bh * DD + e) * NN + n0 + nh * 32 + j * 8) = *(uint4*)tmp;
        }
    }
}

// ---------------- flash attention, split-K x2, 32 q-rows/wave ----------------
// grid (64, 8): x = ((b*16 + qt)*2 + ks), y = h  (h-siblings 64 apart -> same XCD)
// block 256 = 4 waves x 32 q-rows = 128 q-rows. TK=32 double-buffered via
// global_load_lds with XOR swizzle (identical scheme to round 3).
// Each kf/vf B-fragment feeds 2 MFMAs (2 q-groups) -> LDS reads/FLOP halved.
__global__ __launch_bounds__(256, 2) void attn_kernel(
    const unsigned short* __restrict__ Q,
    const unsigned short* __restrict__ K,
    const unsigned short* __restrict__ Vt,
    const unsigned short* __restrict__ adjs,   // bf16 [B][N][N]
    _Float16* __restrict__ Opart,              // [2][BH][N][D] fp16 partials
    float* __restrict__ Lpart)                 // [2][BH][N] fp32 partial row-sums
{
    const int x = blockIdx.x;
    const int h = blockIdx.y;
    const int ks = x & 1, qt = (x >> 1) & 15, b = x >> 5;
    const int bh = b * HH + h;
    const int q0 = qt * 128;
    const int kstart = ks * 1024;
    const int tid = threadIdx.x;
    const int lane = tid & 63, wv = tid >> 6;
    const int m = lane & 15, quad = lane >> 4;

    __shared__ unsigned short Kb[2][32 * 128];   // [key][d] swizzled, 8 KB each
    __shared__ unsigned short Vb[2][128 * 32];   // [d][key] swizzled, 8 KB each
    __shared__ unsigned short Plds[4][16 * 40];  // per-wave P (reused per qg), 5 KB
    // total 37.9 KB

    const unsigned short* Kbase = K + (size_t)bh * NN * DD;
    const unsigned short* Vbase = Vt + (size_t)bh * DD * NN;

    // Q fragments: 2 q-groups of 16 rows, register-resident
    bf16x8 qf[2][4];
    #pragma unroll
    for (int qg = 0; qg < 2; ++qg) {
        const unsigned short* Qr = Q + ((size_t)bh * NN + q0 + wv * 32 + qg * 16 + m) * DD;
        #pragma unroll
        for (int kc = 0; kc < 4; ++kc)
            qf[qg][kc] = *(const bf16x8*)(Qr + kc * 32 + quad * 8);
    }

    f32x4 o[2][8];
    #pragma unroll
    for (int qg = 0; qg < 2; ++qg)
        #pragma unroll
        for (int dt = 0; dt < 8; ++dt) o[qg][dt] = (f32x4){0.f, 0.f, 0.f, 0.f};
    float li[2][4] = {{0.f,0.f,0.f,0.f},{0.f,0.f,0.f,0.f}};

    // adj rows for this lane: q0 + wv*32 + qg*16 + quad*4 + reg
    const unsigned short* Abase = adjs + ((size_t)b * NN + q0 + wv * 32 + quad * 4) * NN;

    // staging lane decomposition (identical to round 3)
    const int kr4 = lane >> 4, kc16 = lane & 15;  // K: 4 rows x 16 chunks / instr
    const int vr16 = lane >> 2, vc4 = lane & 3;   // V: 16 rows x 4 chunks / instr

    #define STAGE(buf, kbase_)                                                              \
        {                                                                                   \
            _Pragma("unroll")                                                               \
            for (int j2 = 0; j2 < 2; ++j2) {                                                \
                const int j = wv * 2 + j2;                                                  \
                const int krow = j * 4 + kr4;                                               \
                gl_lds16(Kbase + (size_t)((kbase_) + krow) * DD + ((kc16 ^ (krow & 15)) * 8),\
                         &Kb[buf][j * 512]);                                                \
                const int vrow = j * 16 + vr16;                                             \
                gl_lds16(Vbase + (size_t)vrow * NN + (kbase_) + ((vc4 ^ ((vr16 >> 1) & 3)) * 8),\
                         &Vb[buf][j * 512]);                                                \
            }                                                                               \
        }

    STAGE(0, kstart);
    __syncthreads();   // vmcnt drain -> tile 0 ready

    for (int kt = 0; kt < 32; ++kt) {
        const int cb = kt & 1, nb = cb ^ 1;
        const int k0 = kstart + kt * 32;

        // adj (bf16) for current tile, both q-groups
        float areg[2][2][4];
        #pragma unroll
        for (int qg = 0; qg < 2; ++qg)
            #pragma unroll
            for (int nt = 0; nt < 2; ++nt)
                #pragma unroll
                for (int reg = 0; reg < 4; ++reg)
                    areg[qg][nt][reg] =
                        bf2f(Abase[(size_t)(qg * 16 + reg) * NN + k0 + nt * 16 + m]) * SCALE;

        // async-stage next tile (no wait; barrier at loop end drains)
        if (kt + 1 < 32) STAGE(nb, k0 + 32);

        #pragma unroll
        for (int qg = 0; qg < 2; ++qg) {
            // QK^T : 8 MFMA per q-group
            f32x4 s[2];
            s[0] = (f32x4){0.f, 0.f, 0.f, 0.f};
            s[1] = (f32x4){0.f, 0.f, 0.f, 0.f};
            #pragma unroll
            for (int kc = 0; kc < 4; ++kc) {
                #pragma unroll
                for (int nt = 0; nt < 2; ++nt) {
                    bf16x8 kf = *(const bf16x8*)&Kb[cb][(nt * 16 + m) * 128 + (((kc * 4 + quad) ^ m) * 8)];
                    s[nt] = __builtin_amdgcn_mfma_f32_16x16x32_bf16(qf[qg][kc], kf, s[nt], 0, 0, 0);
                }
            }

            // p = exp(s*scale*adj)  (no max subtraction: scores bounded)
            #pragma unroll
            for (int nt = 0; nt < 2; ++nt) {
                #pragma unroll
                for (int reg = 0; reg < 4; ++reg) {
                    float p = __expf(s[nt][reg] * areg[qg][nt][reg]);
                    li[qg][reg] += p;
                    Plds[wv][(quad * 4 + reg) * 40 + nt * 16 + m] = f2bf(p);
                }
            }

            // P x V : 8 MFMA per q-group (same-wave LDS dep, no barrier needed)
            bf16x8 pf = *(const bf16x8*)&Plds[wv][m * 40 + quad * 8];
            #pragma unroll
            for (int dt = 0; dt < 8; ++dt) {
                bf16x8 vf = *(const bf16x8*)&Vb[cb][(dt * 16 + m) * 32 + ((quad ^ ((m >> 1) & 3)) * 8)];
                o[qg][dt] = __builtin_amdgcn_mfma_f32_16x16x32_bf16(pf, vf, o[qg][dt], 0, 0, 0);
            }
        }

        __syncthreads();  // readers done with cb; stage(nb) drained
    }
    #undef STAGE

    #pragma unroll
    for (int qg = 0; qg < 2; ++qg) {
        #pragma unroll
        for (int reg = 0; reg < 4; ++reg) {
            float t = li[qg][reg];
            t += __shfl_xor(t, 1);
            t += __shfl_xor(t, 2);
            t += __shfl_xor(t, 4);
            t += __shfl_xor(t, 8);
            li[qg][reg] = t;
        }
        const int rbase = q0 + wv * 32 + qg * 16 + quad * 4;
        if (m == 0) {
            #pragma unroll
            for (int reg = 0; reg < 4; ++reg)
                Lpart[((size_t)ks * (BB * HH) + bh) * NN + rbase + reg] = li[qg][reg];
        }
        #pragma unroll
        for (int reg = 0; reg < 4; ++reg) {
            const size_t obase = (((size_t)ks * (BB * HH) + bh) * NN + rbase + reg) * DD;
            #pragma unroll
            for (int dt = 0; dt < 8; ++dt)
                Opart[obase + dt * 16 + m] = (_Float16)o[qg][dt][reg];
        }
    }
}

// ---------------- fused combine + output projection ----------------
// out[r][oc] = sum_k ((Op0+Op1)[r][k] / l[head(k)][r]) * WoutT[oc][k] + bout[oc]
// grid (64, 4); block 256. k-chunk kc == head kc (128 each).
__global__ __launch_bounds__(256) void out_kernel(
    const _Float16* __restrict__ Op,        // [2][BH][N][D]
    const float* __restrict__ Lp,           // [2][BH][N]
    const unsigned short* __restrict__ WoutT,   // [OUT][HD]
    const float* __restrict__ bout,
    float* __restrict__ out)
{
    const int m0 = blockIdx.x * 64;
    const int c0 = blockIdx.y * 64;
    const int tid = threadIdx.x;
    const int lane = tid & 63, wv = tid >> 6;
    const int m = lane & 15, quad = lane >> 4;

    __shared__ unsigned short Wlds[64 * 136];

    f32x4 acc[4];
    #pragma unroll
    for (int nt = 0; nt < 4; ++nt) acc[nt] = (f32x4){0.f, 0.f, 0.f, 0.f};

    const int r = m0 + wv * 16 + m;       // token row
    const int b = r >> 11, n = r & (NN - 1);

    for (int kc = 0; kc < 8; ++kc) {      // k-chunk == head
        #pragma unroll
        for (int i = tid; i < 64 * 16; i += 256) {
            int rr = i >> 4, c = i & 15;
            *(uint4*)&Wlds[rr * 136 + c * 8] =
                *(const uint4*)(WoutT + (size_t)(c0 + rr) * (HH * DD) + kc * 128 + c * 8);
        }
        const int bh = b * HH + kc;
        const float linv = 1.0f / (Lp[(size_t)bh * NN + n] +
                                   Lp[(size_t)(BB * HH + bh) * NN + n]);
        const size_t obase0 = ((size_t)bh * NN + n) * DD;
        const size_t obase1 = ((size_t)(BB * HH + bh) * NN + n) * DD;
        __syncthreads();
        #pragma unroll
        for (int j = 0; j < 4; ++j) {
            f16x8 a0 = *(const f16x8*)(Op + obase0 + j * 32 + quad * 8);
            f16x8 a1 = *(const f16x8*)(Op + obase1 + j * 32 + quad * 8);
            unsigned short pa[8];
            #pragma unroll
            for (int i = 0; i < 8; ++i)
                pa[i] = f2bf(((float)a0[i] + (float)a1[i]) * linv);
            bf16x8 afr = *(const bf16x8*)pa;
            #pragma unroll
            for (int nt = 0; nt < 4; ++nt) {
                bf16x8 bfr = *(const bf16x8*)&Wlds[(nt * 16 + m) * 136 + j * 32 + quad * 8];
                acc[nt] = __builtin_amdgcn_mfma_f32_16x16x32_bf16(afr, bfr, acc[nt], 0, 0, 0);
            }
        }
        __syncthreads();
    }

    #pragma unroll
    for (int nt = 0; nt < 4; ++nt) {
        int oc = c0 + nt * 16 + m;
        float bb = bout[oc];
        #pragma unroll
        for (int reg = 0; reg < 4; ++reg) {
            int rr = m0 + wv * 16 + quad * 4 + reg;
            out[(size_t)rr * OUTD + oc] = acc[nt][reg] + bb;
        }
    }
}

extern "C" void kernel_launch(void* const* d_in, const int* in_sizes, int n_in,
                              void* d_out, int out_size, void* d_ws, size_t ws_size,
                              hipStream_t stream)
{
    const float* X    = (const float*)d_in[0];
    const float* adj  = (const float*)d_in[1];
    const float* Wq   = (const float*)d_in[2];
    const float* bq   = (const float*)d_in[3];
    const float* Wk   = (const float*)d_in[4];
    const float* bk   = (const float*)d_in[5];
    const float* Wv   = (const float*)d_in[6];
    const float* bv   = (const float*)d_in[7];
    const float* Wout = (const float*)d_in[8];
    const float* bout = (const float*)d_in[9];
    float* out = (float*)d_out;

    char* ws = (char*)d_ws;
    unsigned short* Xb    = (unsigned short*)(ws);             // 1,048,576 B (dead after proj)
    unsigned short* WT    = (unsigned short*)(ws + 1048576);   //   786,432 B
    unsigned short* WoutT = (unsigned short*)(ws + 1835008);   //   524,288 B
    unsigned short* Q     = (unsigned short*)(ws + 2359296);   // 8,388,608 B
    unsigned short* Kp    = (unsigned short*)(ws + 10747904);  // 8,388,608 B
    unsigned short* Vt    = (unsigned short*)(ws + 19136512);  // 8,388,608 B
    unsigned short* AsumB = (unsigned short*)(ws + 27525120);  // 16,777,216 B
    _Float16*       Opart = (_Float16*)(ws + 44302336);        // 16,777,216 B (ends 61,079,552)
    float*          Lpart = (float*)(ws);                      // 262,144 B, reuses dead Xb region

    prep_kernel<<<4608, 256, 0, stream>>>(X, Wq, Wk, Wv, Wout, Xb, WT, WoutT);
    adjsum_kernel<<<(BB * NN * NN) / 256, 256, 0, stream>>>((const float4*)adj, AsumB);
    proj_kernel<<<dim3(NN / 64, BB * HH, 3), 256, 0, stream>>>(Xb, WT, bq, bk, bv, Q, Kp, Vt);
    attn_kernel<<<dim3(64, HH), 256, 0, stream>>>(Q, Kp, Vt, AsumB, Opart, Lpart);
    out_kernel<<<dim3((BB * NN) / 64, OUTD / 64), 256, 0, stream>>>(Opart, Lpart, WoutT, bout, out);
}

// Round 5
// 312.625 us; speedup vs baseline: 1.0053x; 1.0053x over previous
//
#include <hip/hip_runtime.h>
#include <hip/hip_bf16.h>

#define BB 2
#define NN 2048
#define DD 128
#define HH 8
#define OUTD 256
#define SCALE 0.022097086912079612f  // 1/sqrt(2048)

typedef __bf16 bf16x8 __attribute__((ext_vector_type(8)));
typedef float f32x4 __attribute__((ext_vector_type(4)));
typedef _Float16 f16x4 __attribute__((ext_vector_type(4)));

__device__ __forceinline__ unsigned short f2bf(float f) {
    union { float f; unsigned int u; } v; v.f = f;
    unsigned int r = (v.u + 0x7FFFu + ((v.u >> 16) & 1u)) >> 16;
    return (unsigned short)r;
}
__device__ __forceinline__ float bf2f(unsigned short s) {
    union { unsigned int u; float f; } v; v.u = ((unsigned int)s) << 16;
    return v.f;
}
// async global->LDS, 16 B per lane; lds dst = wave-uniform base + lane*16
__device__ __forceinline__ void gl_lds16(const unsigned short* g, unsigned short* l) {
    __builtin_amdgcn_global_load_lds(
        (const __attribute__((address_space(1))) unsigned int*)g,
        (__attribute__((address_space(3))) unsigned int*)l,
        16, 0, 0);
}

// ---------------- prep: Xb cast + coalesced weight transposes ----------------
// grid 552: [0,512) Xb cast (float4), [512,536) WT transpose (mat,h), [536,552) WoutT
__global__ __launch_bounds__(256) void prep_kernel(
    const float* __restrict__ X,
    const float* __restrict__ Wq,
    const float* __restrict__ Wk,
    const float* __restrict__ Wv,
    const float* __restrict__ Wout,
    unsigned short* __restrict__ Xb,     // [B][N][D]
    unsigned short* __restrict__ WT,     // [3][H][e][d]
    unsigned short* __restrict__ WoutT)  // [OUT][H*D]
{
    __shared__ unsigned short T[128 * 136];   // 34,816 B, reused by both transposes
    const int bid = blockIdx.x;
    const int t = threadIdx.x;

    if (bid < 512) {                          // Xb cast, vectorized
        int i4 = (bid * 256 + t) * 4;
        float4 v = *(const float4*)(X + i4);
        unsigned short u[4] = {f2bf(v.x), f2bf(v.y), f2bf(v.z), f2bf(v.w)};
        *(ushort4*)(Xb + i4) = *(const ushort4*)u;
    } else if (bid < 536) {                   // WT: [h][d][e] -> [mat][h][e][d]
        const int mh = bid - 512;
        const int mat = mh >> 3, h = mh & 7;
        const float* Wm = (mat == 0) ? Wq : ((mat == 1) ? Wk : Wv);
        Wm += (size_t)h * DD * DD;
        #pragma unroll
        for (int i = 0; i < 16; ++i) {        // coalesced read 128x128 f32
            int lin = i * 256 + t;
            int d = lin >> 5, e = (lin & 31) * 4;
            float4 v = *(const float4*)(Wm + (size_t)d * DD + e);
            unsigned short u[4] = {f2bf(v.x), f2bf(v.y), f2bf(v.z), f2bf(v.w)};
            *(uint2*)&T[d * 136 + e] = *(const uint2*)u;
        }
        __syncthreads();
        const int e = t >> 1, nh = t & 1;     // write rows e, 64 d each
        unsigned short* Wo = WT + ((size_t)mat * HH + h) * (DD * DD) + (size_t)e * DD + nh * 64;
        #pragma unroll
        for (int j = 0; j < 8; ++j) {
            unsigned short tmp[8];
            #pragma unroll
            for (int k = 0; k < 8; ++k)
                tmp[k] = T[(nh * 64 + j * 8 + k) * 136 + e];
            *(uint4*)(Wo + j * 8) = *(const uint4*)tmp;
        }
    } else {                                  // WoutT: [k][o] -> [o][k]
        const int kb = bid - 536;             // k-block of 64 rows
        #pragma unroll
        for (int i = 0; i < 16; ++i) {        // coalesced read 64x256 f32
            int lin = i * 256 + t;
            int k = lin >> 6, o = (lin & 63) * 4;
            float4 v = *(const float4*)(Wout + (size_t)(kb * 64 + k) * OUTD + o);
            unsigned short u[4] = {f2bf(v.x), f2bf(v.y), f2bf(v.z), f2bf(v.w)};
            *(uint2*)&T[k * 264 + o] = *(const uint2*)u;
        }
        __syncthreads();
        unsigned short* Wo = WoutT + (size_t)t * (HH * DD) + kb * 64;  // row o = t
        #pragma unroll
        for (int j = 0; j < 8; ++j) {
            unsigned short tmp[8];
            #pragma unroll
            for (int k = 0; k < 8; ++k)
                tmp[k] = T[(j * 8 + k) * 264 + t];
            *(uint4*)(Wo + j * 8) = *(const uint4*)tmp;
        }
    }
}

// ---------------- adjsum: nodeadj.sum(-1) -> bf16 ----------------
__global__ void adjsum_kernel(const float4* __restrict__ adj, unsigned short* __restrict__ s) {
    int idx = blockIdx.x * blockDim.x + threadIdx.x;  // B*N*N threads
    float4 a = adj[idx];
    s[idx] = f2bf((a.x + a.y) + (a.z + a.w));
}

// ---------------- projections q/k/v ----------------
// grid (N/64, B*H, 3); block 256. mat: 0=Q, 1=K, 2=V(transposed output via LDS)
__global__ __launch_bounds__(256) void proj_kernel(
    const unsigned short* __restrict__ Xb,
    const unsigned short* __restrict__ WT,
    const float* __restrict__ bq, const float* __restrict__ bk, const float* __restrict__ bv,
    unsigned short* __restrict__ Qo, unsigned short* __restrict__ Ko,
    unsigned short* __restrict__ Vt)
{
    const int mat = blockIdx.z;
    const int bh  = blockIdx.y;
    const int b = bh >> 3, h = bh & 7;
    const int n0 = blockIdx.x * 64;
    const int tid = threadIdx.x;
    const int lane = tid & 63, wv = tid >> 6;
    const int m = lane & 15, quad = lane >> 4;

    __shared__ unsigned short Wlds[128 * 136];  // [e][d], pad 136; reused for V transpose

    const unsigned short* Wg = WT + ((size_t)mat * HH + h) * (DD * DD);
    #pragma unroll
    for (int i = tid; i < 128 * 16; i += 256) {
        int r = i >> 4, c = i & 15;
        *(uint4*)&Wlds[r * 136 + c * 8] = *(const uint4*)(Wg + r * 128 + c * 8);
    }

    const int row = n0 + wv * 16 + m;
    const unsigned short* Xr = Xb + ((size_t)b * NN + row) * DD;
    bf16x8 af[4];
    #pragma unroll
    for (int kc = 0; kc < 4; ++kc)
        af[kc] = *(const bf16x8*)(Xr + kc * 32 + quad * 8);

    __syncthreads();

    f32x4 acc[8];
    #pragma unroll
    for (int et = 0; et < 8; ++et) acc[et] = (f32x4){0.f, 0.f, 0.f, 0.f};

    #pragma unroll
    for (int kc = 0; kc < 4; ++kc) {
        #pragma unroll
        for (int et = 0; et < 8; ++et) {
            bf16x8 bfrg = *(const bf16x8*)&Wlds[(et * 16 + m) * 136 + kc * 32 + quad * 8];
            acc[et] = __builtin_amdgcn_mfma_f32_16x16x32_bf16(af[kc], bfrg, acc[et], 0, 0, 0);
        }
    }

    const float* bias = (mat == 0) ? bq : ((mat == 1) ? bk : bv);
    if (mat != 2) {
        #pragma unroll
        for (int et = 0; et < 8; ++et) {
            int e = et * 16 + m;
            float bb = bias[h * DD + e];
            #pragma unroll
            for (int reg = 0; reg < 4; ++reg) {
                int r = n0 + wv * 16 + quad * 4 + reg;
                unsigned short v16 = f2bf(acc[et][reg] + bb);
                if (mat == 0) Qo[((size_t)bh * NN + r) * DD + e] = v16;
                else          Ko[((size_t)bh * NN + r) * DD + e] = v16;
            }
        }
    } else {
        // V: transpose through LDS -> coalesced uint4 stores to Vt[bh][e][n]
        __syncthreads();  // everyone done with Wlds MFMA reads
        #pragma unroll
        for (int et = 0; et < 8; ++et) {
            int e = et * 16 + m;
            float bb = bias[h * DD + e];
            #pragma unroll
            for (int reg = 0; reg < 4; ++reg)
                Wlds[(wv * 16 + quad * 4 + reg) * 136 + e] = f2bf(acc[et][reg] + bb);
        }
        __syncthreads();
        const int e = tid >> 1, nh = tid & 1;
        #pragma unroll
        for (int j = 0; j < 4; ++j) {
            unsigned short tmp[8];
            #pragma unroll
            for (int kk = 0; kk < 8; ++kk)
                tmp[kk] = Wlds[(nh * 32 + j * 8 + kk) * 136 + e];
            *(uint4*)(Vt + ((size_t)bh * DD + e) * NN + n0 + nh * 32 + j * 8) = *(uint4*)tmp;
        }
    }
}

// ---------------- flash attention, split-K x2, 32 q-rows/wave, XCD-swizzled ----------------
// grid 512 (1-D). Linear id L: xcd = L&7 -> (b, ks, h-hi); W = L>>3 -> (h-lo, qt).
// Assuming id%8 round-robin XCD dispatch: all 16 qt-siblings (share K/V half) and
// 4 h-siblings (share adj rows) land on ONE XCD -> L2 de-dup of K/V and adj refetch.
// kf/vf fragments loaded ONCE and fed to both q-groups (explicit reuse, no CSE needed).
__global__ __launch_bounds__(256, 2) void attn_kernel(
    const unsigned short* __restrict__ Q,
    const unsigned short* __restrict__ K,
    const unsigned short* __restrict__ Vt,
    const unsigned short* __restrict__ adjs,   // bf16 [B][N][N]
    _Float16* __restrict__ Opart,              // [2][BH][N][D] fp16 partials
    float* __restrict__ Lpart)                 // [2][BH][N] fp32 partial row-sums
{
    const int L = blockIdx.x;
    const int xcd = L & 7, W = L >> 3;
    const int b  = (xcd >> 2) & 1;
    const int ks = (xcd >> 1) & 1;
    const int h  = (xcd & 1) * 4 + (W & 3);
    const int qt = W >> 2;                    // [0,16)
    const int bh = b * HH + h;
    const int q0 = qt * 128;
    const int kstart = ks * 1024;
    const int tid = threadIdx.x;
    const int lane = tid & 63, wv = tid >> 6;
    const int m = lane & 15, quad = lane >> 4;

    __shared__ unsigned short Kb[2][32 * 128];    // [key][d] swizzled, 8 KB each
    __shared__ unsigned short Vb[2][128 * 32];    // [d][key] swizzled, 8 KB each
    __shared__ unsigned short Plds[4][2][16 * 40];// per-wave, per-q-group P -> 10 KB
    // total 42 KB

    const unsigned short* Kbase = K + (size_t)bh * NN * DD;
    const unsigned short* Vbase = Vt + (size_t)bh * DD * NN;

    // Q fragments: 2 q-groups of 16 rows, register-resident
    bf16x8 qf[2][4];
    #pragma unroll
    for (int qg = 0; qg < 2; ++qg) {
        const unsigned short* Qr = Q + ((size_t)bh * NN + q0 + wv * 32 + qg * 16 + m) * DD;
        #pragma unroll
        for (int kc = 0; kc < 4; ++kc)
            qf[qg][kc] = *(const bf16x8*)(Qr + kc * 32 + quad * 8);
    }

    f32x4 o[2][8];
    #pragma unroll
    for (int qg = 0; qg < 2; ++qg)
        #pragma unroll
        for (int dt = 0; dt < 8; ++dt) o[qg][dt] = (f32x4){0.f, 0.f, 0.f, 0.f};
    float li[2][4] = {{0.f,0.f,0.f,0.f},{0.f,0.f,0.f,0.f}};

    // adj rows for this lane: q0 + wv*32 + qg*16 + quad*4 + reg
    const unsigned short* Abase = adjs + ((size_t)b * NN + q0 + wv * 32 + quad * 4) * NN;

    // staging lane decomposition
    const int kr4 = lane >> 4, kc16 = lane & 15;  // K: 4 rows x 16 chunks / instr
    const int vr16 = lane >> 2, vc4 = lane & 3;   // V: 16 rows x 4 chunks / instr

    #define STAGE(buf, kbase_)                                                              \
        {                                                                                   \
            _Pragma("unroll")                                                               \
            for (int j2 = 0; j2 < 2; ++j2) {                                                \
                const int j = wv * 2 + j2;                                                  \
                const int krow = j * 4 + kr4;                                               \
                gl_lds16(Kbase + (size_t)((kbase_) + krow) * DD + ((kc16 ^ (krow & 15)) * 8),\
                         &Kb[buf][j * 512]);                                                \
                const int vrow = j * 16 + vr16;                                             \
                gl_lds16(Vbase + (size_t)vrow * NN + (kbase_) + ((vc4 ^ ((vr16 >> 1) & 3)) * 8),\
                         &Vb[buf][j * 512]);                                                \
            }                                                                               \
        }

    STAGE(0, kstart);
    __syncthreads();   // vmcnt drain -> tile 0 ready

    for (int kt = 0; kt < 32; ++kt) {
        const int cb = kt & 1, nb = cb ^ 1;
        const int k0 = kstart + kt * 32;

        // adj (bf16) for current tile, both q-groups (issued before staging loads
        // so their vmcnt wait doesn't drain the prefetch)
        float areg[2][2][4];
        #pragma unroll
        for (int qg = 0; qg < 2; ++qg)
            #pragma unroll
            for (int nt = 0; nt < 2; ++nt)
                #pragma unroll
                for (int reg = 0; reg < 4; ++reg)
                    areg[qg][nt][reg] =
                        bf2f(Abase[(size_t)(qg * 16 + reg) * NN + k0 + nt * 16 + m]) * SCALE;

        // async-stage next tile (no wait; barrier at loop end drains)
        if (kt + 1 < 32) STAGE(nb, k0 + 32);

        // QK^T: each kf fragment feeds BOTH q-groups (16 MFMA, 8 kf loads)
        f32x4 s[2][2];
        s[0][0] = (f32x4){0.f,0.f,0.f,0.f}; s[0][1] = (f32x4){0.f,0.f,0.f,0.f};
        s[1][0] = (f32x4){0.f,0.f,0.f,0.f}; s[1][1] = (f32x4){0.f,0.f,0.f,0.f};
        #pragma unroll
        for (int kc = 0; kc < 4; ++kc) {
            #pragma unroll
            for (int nt = 0; nt < 2; ++nt) {
                bf16x8 kf = *(const bf16x8*)&Kb[cb][(nt * 16 + m) * 128 + (((kc * 4 + quad) ^ m) * 8)];
                s[0][nt] = __builtin_amdgcn_mfma_f32_16x16x32_bf16(qf[0][kc], kf, s[0][nt], 0, 0, 0);
                s[1][nt] = __builtin_amdgcn_mfma_f32_16x16x32_bf16(qf[1][kc], kf, s[1][nt], 0, 0, 0);
            }
        }

        // p = exp(s*scale*adj)  (no max subtraction: scores bounded)
        #pragma unroll
        for (int qg = 0; qg < 2; ++qg)
            #pragma unroll
            for (int nt = 0; nt < 2; ++nt)
                #pragma unroll
                for (int reg = 0; reg < 4; ++reg) {
                    float p = __expf(s[qg][nt][reg] * areg[qg][nt][reg]);
                    li[qg][reg] += p;
                    Plds[wv][qg][(quad * 4 + reg) * 40 + nt * 16 + m] = f2bf(p);
                }

        // P x V: each vf fragment feeds BOTH q-groups (16 MFMA, 8 vf loads)
        bf16x8 pf0 = *(const bf16x8*)&Plds[wv][0][m * 40 + quad * 8];
        bf16x8 pf1 = *(const bf16x8*)&Plds[wv][1][m * 40 + quad * 8];
        #pragma unroll
        for (int dt = 0; dt < 8; ++dt) {
            bf16x8 vf = *(const bf16x8*)&Vb[cb][(dt * 16 + m) * 32 + ((quad ^ ((m >> 1) & 3)) * 8)];
            o[0][dt] = __builtin_amdgcn_mfma_f32_16x16x32_bf16(pf0, vf, o[0][dt], 0, 0, 0);
            o[1][dt] = __builtin_amdgcn_mfma_f32_16x16x32_bf16(pf1, vf, o[1][dt], 0, 0, 0);
        }

        __syncthreads();  // readers done with cb; stage(nb) drained
    }
    #undef STAGE

    #pragma unroll
    for (int qg = 0; qg < 2; ++qg) {
        #pragma unroll
        for (int reg = 0; reg < 4; ++reg) {
            float t = li[qg][reg];
            t += __shfl_xor(t, 1);
            t += __shfl_xor(t, 2);
            t += __shfl_xor(t, 4);
            t += __shfl_xor(t, 8);
            li[qg][reg] = t;
        }
        const int rbase = q0 + wv * 32 + qg * 16 + quad * 4;
        if (m == 0) {
            #pragma unroll
            for (int reg = 0; reg < 4; ++reg)
                Lpart[((size_t)ks * (BB * HH) + bh) * NN + rbase + reg] = li[qg][reg];
        }
        #pragma unroll
        for (int reg = 0; reg < 4; ++reg) {
            const size_t obase = (((size_t)ks * (BB * HH) + bh) * NN + rbase + reg) * DD;
            #pragma unroll
            for (int dt = 0; dt < 8; ++dt)
                Opart[obase + dt * 16 + m] = (_Float16)o[qg][dt][reg];
        }
    }
}

// ---------------- combine split-K partials -> Ocat bf16 ----------------
__global__ void combine_kernel(const _Float16* __restrict__ Op,
                               const float* __restrict__ Lp,
                               unsigned short* __restrict__ Ocat)
{
    const int SPLIT_OFF = BB * HH * NN * DD;   // 4,194,304
    int t = blockIdx.x * blockDim.x + threadIdx.x;
    int e0 = t * 4;
    int row = e0 >> 7;                         // bh*N + n
    float l = 1.0f / (Lp[row] + Lp[row + BB * HH * NN]);
    f16x4 a = *(const f16x4*)(Op + e0);
    f16x4 c = *(const f16x4*)(Op + SPLIT_OFF + e0);
    int bh = row >> 11, n = row & (NN - 1);
    int b = bh >> 3, h = bh & 7;
    size_t obase = ((size_t)(b * NN + n)) * (HH * DD) + h * DD + (e0 & (DD - 1));
    unsigned short u[4];
    #pragma unroll
    for (int i = 0; i < 4; ++i)
        u[i] = f2bf(((float)a[i] + (float)c[i]) * l);
    *(ushort4*)(Ocat + obase) = *(ushort4*)u;
}

// ---------------- output projection: [4096 x 1024] @ [1024 x 256] + bout ----------------
// grid (128, 4) = 512 blocks (2/CU). M-tile 32, N-tile 64. Wave w: rows (w&1)*16, cols (w>>1)*32.
__global__ __launch_bounds__(256) void out_kernel(
    const unsigned short* __restrict__ Ocat,
    const unsigned short* __restrict__ WoutT,   // [OUT][HD]
    const float* __restrict__ bout,
    float* __restrict__ out)
{
    const int m0 = blockIdx.x * 32;
    const int c0 = blockIdx.y * 64;
    const int tid = threadIdx.x;
    const int lane = tid & 63, wv = tid >> 6;
    const int m = lane & 15, quad = lane >> 4;
    const int mg = wv & 1, cg = wv >> 1;

    __shared__ unsigned short Wlds[64 * 136];

    f32x4 acc[2];
    acc[0] = (f32x4){0.f,0.f,0.f,0.f};
    acc[1] = (f32x4){0.f,0.f,0.f,0.f};

    const unsigned short* Orow = Ocat + (size_t)(m0 + mg * 16 + m) * (HH * DD);

    for (int kc = 0; kc < 8; ++kc) {
        #pragma unroll
        for (int i = tid; i < 64 * 16; i += 256) {
            int rr = i >> 4, c = i & 15;
            *(uint4*)&Wlds[rr * 136 + c * 8] =
                *(const uint4*)(WoutT + (size_t)(c0 + rr) * (HH * DD) + kc * 128 + c * 8);
        }
        __syncthreads();
        #pragma unroll
        for (int j = 0; j < 4; ++j) {
            bf16x8 afr = *(const bf16x8*)(Orow + kc * 128 + j * 32 + quad * 8);
            #pragma unroll
            for (int nt = 0; nt < 2; ++nt) {
                bf16x8 bfr = *(const bf16x8*)&Wlds[(cg * 32 + nt * 16 + m) * 136 + j * 32 + quad * 8];
                acc[nt] = __builtin_amdgcn_mfma_f32_16x16x32_bf16(afr, bfr, acc[nt], 0, 0, 0);
            }
        }
        __syncthreads();
    }

    #pragma unroll
    for (int nt = 0; nt < 2; ++nt) {
        int oc = c0 + cg * 32 + nt * 16 + m;
        float bb = bout[oc];
        #pragma unroll
        for (int reg = 0; reg < 4; ++reg) {
            int rr = m0 + mg * 16 + quad * 4 + reg;
            out[(size_t)rr * OUTD + oc] = acc[nt][reg] + bb;
        }
    }
}

extern "C" void kernel_launch(void* const* d_in, const int* in_sizes, int n_in,
                              void* d_out, int out_size, void* d_ws, size_t ws_size,
                              hipStream_t stream)
{
    const float* X    = (const float*)d_in[0];
    const float* adj  = (const float*)d_in[1];
    const float* Wq   = (const float*)d_in[2];
    const float* bq   = (const float*)d_in[3];
    const float* Wk   = (const float*)d_in[4];
    const float* bk   = (const float*)d_in[5];
    const float* Wv   = (const float*)d_in[6];
    const float* bv   = (const float*)d_in[7];
    const float* Wout = (const float*)d_in[8];
    const float* bout = (const float*)d_in[9];
    float* out = (float*)d_out;

    char* ws = (char*)d_ws;
    unsigned short* Xb    = (unsigned short*)(ws);             // 1,048,576 B (dead after proj)
    unsigned short* WT    = (unsigned short*)(ws + 1048576);   //   786,432 B
    unsigned short* WoutT = (unsigned short*)(ws + 1835008);   //   524,288 B
    unsigned short* Q     = (unsigned short*)(ws + 2359296);   // 8,388,608 B
    unsigned short* Kp    = (unsigned short*)(ws + 10747904);  // 8,388,608 B
    unsigned short* Vt    = (unsigned short*)(ws + 19136512);  // 8,388,608 B
    unsigned short* AsumB = (unsigned short*)(ws + 27525120);  // 16,777,216 B
    _Float16*       Opart = (_Float16*)(ws + 44302336);        // 16,777,216 B
    unsigned short* Ocat  = (unsigned short*)(ws + 61079552);  // 8,388,608 B (ends 69,468,160)
    float*          Lpart = (float*)(ws);                      // 262,144 B, reuses dead Xb region

    prep_kernel<<<552, 256, 0, stream>>>(X, Wq, Wk, Wv, Wout, Xb, WT, WoutT);
    adjsum_kernel<<<(BB * NN * NN) / 256, 256, 0, stream>>>((const float4*)adj, AsumB);
    proj_kernel<<<dim3(NN / 64, BB * HH, 3), 256, 0, stream>>>(Xb, WT, bq, bk, bv, Q, Kp, Vt);
    attn_kernel<<<512, 256, 0, stream>>>(Q, Kp, Vt, AsumB, Opart, Lpart);
    combine_kernel<<<(BB * HH * NN * DD / 4) / 256, 256, 0, stream>>>(Opart, Lpart, Ocat);
    out_kernel<<<dim3((BB * NN) / 32, OUTD / 64), 256, 0, stream>>>(Ocat, WoutT, bout, out);
}